// Round 14
// baseline (354.835 us; speedup 1.0000x reference)
//
#include <hip/hip_runtime.h>
#include <hip/hip_bf16.h>
#include <math.h>

#define T_SEQ 4096
#define C_DIM 128
#define B_SZ  4

typedef __attribute__((ext_vector_type(8))) short short8;
typedef __attribute__((ext_vector_type(4))) short short4v;
typedef __attribute__((ext_vector_type(4))) float f32x4;

__device__ __forceinline__ short f2bf(float f) {
    union { float fv; unsigned u; } v; v.fv = f;
    unsigned r = v.u + 0x7fff + ((v.u >> 16) & 1);
    return (short)(r >> 16);
}

__device__ __forceinline__ unsigned pk_bf16(float a, float b) {
    union { __hip_bfloat162 h2; unsigned u; } c;
    c.h2 = __float22bfloat162_rn(make_float2(a, b));
    return c.u;
}

__device__ __forceinline__ short8 load_f32x8_bf16(const float* p) {
    const float4* q = (const float4*)p;
    float4 a = q[0], b = q[1];
    short8 r;
    r[0] = f2bf(a.x); r[1] = f2bf(a.y); r[2] = f2bf(a.z); r[3] = f2bf(a.w);
    r[4] = f2bf(b.x); r[5] = f2bf(b.y); r[6] = f2bf(b.z); r[7] = f2bf(b.w);
    return r;
}

// 16B-per-lane async global->LDS DMA (wave-uniform LDS base + lane*16).
__device__ __forceinline__ void async_cp16(const short* g, short* l) {
    __builtin_amdgcn_global_load_lds(
        (const __attribute__((address_space(1))) unsigned int*)g,
        (__attribute__((address_space(3))) unsigned int*)l, 16, 0, 0);
}

// ---------------------------------------------------------------------------
// Kernel 1: QKV projection (R23-R25 version). Kf stored KV-PERMUTED per
// 16x16 tile: kv-chunk i32 (32 kv rows) = contiguous 8 KB at Kf + i32*4096
// shorts (Vf likewise) so flash's swapped QK^T output is directly PV's
// A-fragment. R27: block 0 also zeroes the 128 quarter-completion counters
// (one per (gg,b)) used by flash's fold-in combine; stream order makes them
// visible to flash, and they are re-zeroed every graph replay.
// ---------------------------------------------------------------------------
__global__ __launch_bounds__(256) void qkv_proj(
    const float* __restrict__ x, const float* __restrict__ Wq,
    const float* __restrict__ Wk, const float* __restrict__ Wv,
    short* __restrict__ Q, short* __restrict__ Kf, short* __restrict__ Vf,
    unsigned* __restrict__ cnt)
{
    __shared__ short8 Wl[2048];

    const int tid  = threadIdx.x;
    const int lane = tid & 63;
    const int ln15 = lane & 15;
    const int quad = lane >> 4;
    const int mat  = blockIdx.x >> 7;                       // 0..2
    const int rt   = (blockIdx.x & 127) * 4 + (tid >> 6);   // 0..511
    const int m0   = rt * 32;

    if (blockIdx.x == 0 && tid < 128) cnt[tid] = 0u;

    const float* W = (mat == 0) ? Wq : (mat == 1) ? Wk : Wv;

#pragma unroll
    for (int it = 0; it < 8; ++it) {
        int i = tid + it * 256;
        int n = i >> 4, kc = i & 15;
        short8 v = load_f32x8_bf16(W + n * C_DIM + kc * 8);
        Wl[((n >> 4) * 4 + (kc >> 2)) * 64 + (kc & 3) * 16 + (n & 15)] = v;
    }

    short8 afr[2][4];
#pragma unroll
    for (int ms = 0; ms < 2; ++ms) {
        const float* xrow = x + (size_t)(m0 + ms * 16 + ln15) * C_DIM + quad * 8;
#pragma unroll
        for (int ks = 0; ks < 4; ++ks)
            afr[ms][ks] = load_f32x8_bf16(xrow + ks * 32);
    }

    __syncthreads();

    const float scale = (mat == 0) ? (0.08838834764831845f * 1.4426950408889634f)
                                   : 1.0f;
    const int b  = m0 >> 12;
    const int tl = m0 & 4095;

#pragma unroll
    for (int nt = 0; nt < 8; ++nt) {
        f32x4 acc0 = {0.f, 0.f, 0.f, 0.f};
        f32x4 acc1 = {0.f, 0.f, 0.f, 0.f};
#pragma unroll
        for (int ks = 0; ks < 4; ++ks) {
            short8 bfr = Wl[(nt * 4 + ks) * 64 + lane];
            if (mat == 2) {
                acc0 = __builtin_amdgcn_mfma_f32_16x16x32_bf16(afr[0][ks], bfr, acc0, 0, 0, 0);
                acc1 = __builtin_amdgcn_mfma_f32_16x16x32_bf16(afr[1][ks], bfr, acc1, 0, 0, 0);
            } else {
                acc0 = __builtin_amdgcn_mfma_f32_16x16x32_bf16(bfr, afr[0][ks], acc0, 0, 0, 0);
                acc1 = __builtin_amdgcn_mfma_f32_16x16x32_bf16(bfr, afr[1][ks], acc1, 0, 0, 0);
            }
        }
        if (mat == 0) {
            short4v s0, s1;
#pragma unroll
            for (int r = 0; r < 4; ++r) { s0[r] = f2bf(acc0[r] * scale); s1[r] = f2bf(acc1[r] * scale); }
            *(short4v*)&Q[(size_t)(m0 + ln15) * C_DIM + nt * 16 + quad * 4]      = s0;
            *(short4v*)&Q[(size_t)(m0 + 16 + ln15) * C_DIM + nt * 16 + quad * 4] = s1;
        } else if (mat == 1) {
            short4v s0, s1;
#pragma unroll
            for (int r = 0; r < 4; ++r) { s0[r] = f2bf(acc0[r]); s1[r] = f2bf(acc1[r]); }
            const int ks     = nt >> 1;
            const int quad_k = (nt & 1) * 2 + (quad >> 1);
            const int j0     = (quad & 1) * 4;
            // ms = 0
            {
                const int A0 = (tl >> 4) & 3;                 // in {0,2}
                const int rd = tl >> 6;
                const int kt = (A0 >> 1) * 2 + ((ln15 >> 2) & 1);
                const int ar = (((A0 & 1) << 1) | ((ln15 >> 3) & 1)) * 4 + (ln15 & 3);
                size_t a = ((size_t)b << 19) + (size_t)rd * 8192
                         + (kt * 4 + ks) * 512 + quad_k * 128 + ar * 8 + j0;
                *(short4v*)&Kf[a] = s0;
            }
            // ms = 1 (t-base = tl + 16)
            {
                const int A1 = ((tl >> 4) + 1) & 3;           // in {1,3}
                const int rd = (tl + 16) >> 6;
                const int kt = (A1 >> 1) * 2 + ((ln15 >> 2) & 1);
                const int ar = (((A1 & 1) << 1) | ((ln15 >> 3) & 1)) * 4 + (ln15 & 3);
                size_t a = ((size_t)b << 19) + (size_t)rd * 8192
                         + (kt * 4 + ks) * 512 + quad_k * 128 + ar * 8 + j0;
                *(short4v*)&Kf[a] = s1;
            }
        } else {
            const int kvc = tl >> 5;
            short4v s0, s1;
#pragma unroll
            for (int r = 0; r < 4; ++r) { s0[r] = f2bf(acc0[r]); s1[r] = f2bf(acc1[r]); }
            short* vbase = Vf + (((size_t)(b * 128 + kvc) * 8 + nt) << 9);
            *(short4v*)&vbase[((quad >> 1) * 16 + ln15) * 8 + (quad & 1) * 4]       = s0;
            *(short4v*)&vbase[(((quad >> 1) + 2) * 16 + ln15) * 8 + (quad & 1) * 4] = s1;
        }
    }
}

// ---------------------------------------------------------------------------
// Kernel 2: causal flash attention. R27 = R25 (best measured: fused
// chunk-pair, 8 waves/512 thr, complementary-pair balance) + FOLD-IN
// COMBINE: the 4th quarter-block to finish a (gg,b) group sums the 4
// partial planes and writes `out` inline (threadFenceReduction pattern:
// stores -> __threadfence -> atomicAdd(device-scope) -> last block
// acquire-fences and reduces). The separate combine kernel and its launch
// gap are deleted. R26's 4-wave dedup reverted (regressed: TLP loss).
// ---------------------------------------------------------------------------

#define QK8(KARR, SA, SB)                                                    \
    _Pragma("unroll")                                                        \
    for (int ks = 0; ks < 4; ++ks) {                                         \
      SA = __builtin_amdgcn_mfma_f32_16x16x32_bf16(KARR[ks],   qf[ks], SA, 0,0,0); \
      SB = __builtin_amdgcn_mfma_f32_16x16x32_bf16(KARR[4+ks], qf[ks], SB, 0,0,0); \
    }

#define SM8(SA, SB, PA)                                                      \
    {                                                                        \
      float p0 = __builtin_amdgcn_exp2f(SA[0] - 16.f);                       \
      float p1 = __builtin_amdgcn_exp2f(SA[1] - 16.f);                       \
      float p2 = __builtin_amdgcn_exp2f(SA[2] - 16.f);                       \
      float p3 = __builtin_amdgcn_exp2f(SA[3] - 16.f);                       \
      float p4 = __builtin_amdgcn_exp2f(SB[0] - 16.f);                       \
      float p5 = __builtin_amdgcn_exp2f(SB[1] - 16.f);                       \
      float p6 = __builtin_amdgcn_exp2f(SB[2] - 16.f);                       \
      float p7 = __builtin_amdgcn_exp2f(SB[3] - 16.f);                       \
      l_i += ((p0 + p1) + (p2 + p3)) + ((p4 + p5) + (p6 + p7));              \
      PA.u[0] = pk_bf16(p0, p1); PA.u[1] = pk_bf16(p2, p3);                  \
      PA.u[2] = pk_bf16(p4, p5); PA.u[3] = pk_bf16(p6, p7);                  \
    }

#define MASK8(SA, SB, CC)                                                    \
    if (32 * (CC) + 31 > Rw) {                                               \
      const int qcol = Rw + ln15;                                            \
      const int kb   = 32 * (CC) + quad * 8;                                 \
      _Pragma("unroll")                                                      \
      for (int rr = 0; rr < 4; ++rr) {                                       \
        if (kb + rr > qcol)     SA[rr] = -INFINITY;                          \
        if (kb + 4 + rr > qcol) SB[rr] = -INFINITY;                          \
      }                                                                      \
    }

#define PV8(VB_, OFF, PA)                                                    \
    _Pragma("unroll")                                                        \
    for (int dt = 0; dt < 8; ++dt) {                                         \
      short8 vfr = *(const short8*)&(VB_)[(OFF) + dt * 512 + lane * 8];      \
      acc[dt] = __builtin_amdgcn_mfma_f32_16x16x32_bf16(PA.s8, vfr,          \
                                                        acc[dt], 0, 0, 0);   \
    }

// Fused: both chunks of the round active. Chunk0 is never diagonal here.
#define CHUNK2(KB_, VB_, T0)                                                 \
  {                                                                          \
    const int cc1 = qq + 4 * (T0) + 4;                                       \
    short8 kfr0[8];                                                          \
    _Pragma("unroll")                                                        \
    for (int j = 0; j < 8; ++j)                                              \
      kfr0[j] = *(const short8*)&(KB_)[j * 512 + lane * 8];                  \
    __builtin_amdgcn_s_setprio(1);                                           \
    f32x4 Sa0 = {0.f,0.f,0.f,0.f}, Sb0 = {0.f,0.f,0.f,0.f};                  \
    QK8(kfr0, Sa0, Sb0)                                                      \
    short8 kfr1[8];                                                          \
    _Pragma("unroll")                                                        \
    for (int j = 0; j < 8; ++j)                                              \
      kfr1[j] = *(const short8*)&(KB_)[4096 + j * 512 + lane * 8];           \
    f32x4 Sa1 = {0.f,0.f,0.f,0.f}, Sb1 = {0.f,0.f,0.f,0.f};                  \
    QK8(kfr1, Sa1, Sb1)                                                      \
    union { unsigned u[4]; short8 s8; } pa0, pa1;                            \
    SM8(Sa0, Sb0, pa0)                                                       \
    PV8(VB_, 0, pa0)                                                         \
    MASK8(Sa1, Sb1, cc1)                                                     \
    SM8(Sa1, Sb1, pa1)                                                       \
    PV8(VB_, 4096, pa1)                                                      \
    __builtin_amdgcn_s_setprio(0);                                           \
  }

// Single: only chunk0 (slot 0) active.
#define CHUNK1(KB_, VB_, T0)                                                 \
  {                                                                          \
    const int cc0 = qq + 4 * (T0);                                           \
    short8 kfr0[8];                                                          \
    _Pragma("unroll")                                                        \
    for (int j = 0; j < 8; ++j)                                              \
      kfr0[j] = *(const short8*)&(KB_)[j * 512 + lane * 8];                  \
    __builtin_amdgcn_s_setprio(1);                                           \
    f32x4 Sa0 = {0.f,0.f,0.f,0.f}, Sb0 = {0.f,0.f,0.f,0.f};                  \
    QK8(kfr0, Sa0, Sb0)                                                      \
    MASK8(Sa0, Sb0, cc0)                                                     \
    union { unsigned u[4]; short8 s8; } pa0;                                 \
    SM8(Sa0, Sb0, pa0)                                                       \
    PV8(VB_, 0, pa0)                                                         \
    __builtin_amdgcn_s_setprio(0);                                           \
  }

#define ROUND(KC, VC, KN, VN, R)                                             \
  {                                                                          \
    /* TOP: stage(R) complete (issued a full round ago) */                   \
    asm volatile("s_waitcnt vmcnt(0)" ::: "memory");                         \
    __builtin_amdgcn_sched_barrier(0);                                       \
    __builtin_amdgcn_s_barrier();                                            \
    __builtin_amdgcn_sched_barrier(0);                                       \
    /* stage round R+1 (chunks 2R+2, 2R+3) into KN/VN; wave roles:          \
       w0,1->K slot0 | w2,3->K slot1 | w4,5->V slot0 | w6,7->V slot1 */      \
    {                                                                        \
      const int slot = (w >> 1) & 1;                                         \
      const int tS   = 2 * (R) + 2 + slot;                                   \
      if (tS <= gg) {                                                        \
        const int hw = w & 1;                                                \
        const short* src = ((w < 4) ? Kb : Vb)                               \
                         + (size_t)(qq + 4 * tS) * 4096 + hw * 2048;         \
        short* dst = ((w < 4) ? (KN) : (VN)) + slot * 4096 + hw * 2048;      \
        _Pragma("unroll")                                                    \
        for (int i = 0; i < 4; ++i)                                          \
          async_cp16(src + i * 512 + lane * 8, dst + i * 512);               \
      }                                                                      \
    }                                                                        \
    const int t0 = 2 * (R);                                                  \
    const bool a1 = (t0 + 1 <= gg) && (32 * (qq + 4 * t0 + 4) <= Rw + 15);   \
    const bool a0 = (t0 <= gg) && (32 * (qq + 4 * t0) <= Rw + 15);           \
    if (a1)      CHUNK2(KC, VC, t0)                                          \
    else if (a0) CHUNK1(KC, VC, t0)                                          \
  }

__global__ __launch_bounds__(512, 2) void flash_attn(
    const short* __restrict__ Q, const short* __restrict__ Kf,
    const short* __restrict__ Vf, float* __restrict__ part,
    float* __restrict__ lpart, float* __restrict__ out,
    unsigned* __restrict__ cnt)
{
    __shared__ short Kld0[8192];   // 16 KB: 2 kv-chunks (slots), tile-permuted
    __shared__ short Kld1[8192];   // distinct objects: alias-free dbuf
    __shared__ short Vld0[8192];
    __shared__ short Vld1[8192];
    __shared__ unsigned lastflag;

    const int tid  = threadIdx.x;
    const int w    = tid >> 6;            // 0..7 = q-tile owner + stage role
    const int lane = tid & 63;
    const int ln15 = lane & 15;
    const int quad = lane >> 4;
    const int bid  = blockIdx.x;

    // complementary-pair balance: bid and bid+256 share a CU; give them
    // gg = 31-x and x so per-CU round-sum is constant.
    const int u     = bid & 255;
    const int ph    = bid >> 8;           // 0: gg descending; 1: ascending
    const int xg    = u >> 3;             // 0..31
    const int gg    = ph ? xg : (31 - xg);
    const int combo = (ph << 3) | (u & 7);  // 0..15, all (b,qq) per gg
    const int b     = combo >> 2;         // batch
    const int qq    = combo & 3;          // kv chunk parity quarter

    const int Rw   = 128 * gg + 16 * w;   // this wave's 16-row base (in-batch)
    const int nrounds = (gg >> 1) + 1;    // chunks t=0..gg, 2 per round

    const short* Qb = Q  + ((size_t)b << 19);
    const short* Kb = Kf + ((size_t)b << 19);
    const short* Vb = Vf + ((size_t)b << 19);

    // Q B-frags for this wave's 16 q-rows
    short8 qf[4];
    {
        const short* qrow = Qb + (size_t)(Rw + ln15) * C_DIM + quad * 8;
#pragma unroll
        for (int ks = 0; ks < 4; ++ks)
            qf[ks] = *(const short8*)(qrow + ks * 32);
    }

    f32x4 acc[8];
#pragma unroll
    for (int dt = 0; dt < 8; ++dt)
        acc[dt] = (f32x4){0.f, 0.f, 0.f, 0.f};
    float l_i = 0.f;

    // prologue: stage round 0 (chunks t=0 slot0, t=1 slot1) into buf0
    {
        const int slot = (w >> 1) & 1;
        const int tS   = slot;
        if (tS <= gg) {
            const int hw = w & 1;
            const short* src = ((w < 4) ? Kb : Vb)
                             + (size_t)(qq + 4 * tS) * 4096 + hw * 2048;
            short* dst = ((w < 4) ? Kld0 : Vld0) + slot * 4096 + hw * 2048;
#pragma unroll
            for (int i = 0; i < 4; ++i)
                async_cp16(src + i * 512 + lane * 8, dst + i * 512);
        }
    }

    int r = 0;
    while (true) {
        ROUND(Kld0, Vld0, Kld1, Vld1, r);
        if (++r >= nrounds) break;
        ROUND(Kld1, Vld1, Kld0, Vld0, r);
        if (++r >= nrounds) break;
    }

    // ---- epilogue: quad-sum l in-register, store partial O + l ----
    l_i += __shfl_xor(l_i, 16);
    l_i += __shfl_xor(l_i, 32);           // all lanes: full l for q-row ln15

    float* pp = part + (((size_t)(qq * 4 + b)) * 4096 + Rw) * 128;
#pragma unroll
    for (int dt = 0; dt < 8; ++dt)
#pragma unroll
        for (int rr = 0; rr < 4; ++rr)
            pp[(quad * 4 + rr) * 128 + dt * 16 + ln15] = acc[dt][rr];
    if (quad == 0)
        lpart[(size_t)(qq * 4 + b) * 4096 + Rw + ln15] = l_i;

    // ---- fold-in combine: last of the 4 quarter-blocks for (gg,b) ----
    __threadfence();                      // release this block's part/lpart
    __syncthreads();                      // all waves' stores fenced
    if (tid == 0)
        lastflag = atomicAdd(&cnt[gg * 4 + b], 1u);
    __syncthreads();
    if (lastflag == 3u) {
        __threadfence();                  // acquire other quarters' writes
        float* outb = out + ((size_t)b << 19);
#pragma unroll
        for (int i = 0; i < 8; ++i) {
            int f4   = i * 512 + tid;     // 4096 f4 in this 128-row group
            int c4   = f4 & 31;
            int rloc = f4 >> 5;           // 0..127
            int trow = gg * 128 + rloc;
            float4 p = make_float4(0.f, 0.f, 0.f, 0.f);
            float  l = 0.f;
#pragma unroll
            for (int q = 0; q < 4; ++q) {
                size_t base = (((size_t)(q * 4 + b)) * 4096 + trow) * 128 + c4 * 4;
                float4 pq = *(const float4*)&part[base];
                p.x += pq.x; p.y += pq.y; p.z += pq.z; p.w += pq.w;
                l += lpart[(size_t)(q * 4 + b) * 4096 + trow];
            }
            float li = 1.0f / l;
            float4 v;
            v.x = p.x * li; v.y = p.y * li; v.z = p.z * li; v.w = p.w * li;
            *(float4*)&outb[(size_t)trow * 128 + c4 * 4] = v;
        }
    }
}

extern "C" void kernel_launch(void* const* d_in, const int* in_sizes, int n_in,
                              void* d_out, int out_size, void* d_ws, size_t ws_size,
                              hipStream_t stream) {
    const float* x  = (const float*)d_in[0];
    const float* Wq = (const float*)d_in[1];
    const float* Wk = (const float*)d_in[2];
    const float* Wv = (const float*)d_in[3];
    float* out = (float*)d_out;

    const size_t elems = (size_t)B_SZ * T_SEQ * C_DIM;   // 2,097,152
    short* Q  = (short*)d_ws;
    short* Kf = Q  + elems;
    short* Vf = Kf + elems;
    float* part  = (float*)(Vf + elems);                 // 16 planes x 2 MB
    float* lpart = part + (size_t)16 * 4096 * 128;
    unsigned* cnt = (unsigned*)(lpart + (size_t)16 * 4096);  // 128 counters

    hipLaunchKernelGGL(qkv_proj, dim3(384), dim3(256), 0, stream,
                       x, Wq, Wk, Wv, Q, Kf, Vf, cnt);
    // 512 blocks, complementary-pair balanced; last quarter-block per
    // (gg,b) group folds the combine in (no third kernel).
    hipLaunchKernelGGL(flash_attn, dim3(512), dim3(512), 0, stream,
                       Q, Kf, Vf, part, lpart, out, cnt);
}

// Round 15
// 110.845 us; speedup vs baseline: 3.2012x; 3.2012x over previous
//
#include <hip/hip_runtime.h>
#include <hip/hip_bf16.h>
#include <math.h>

#define T_SEQ 4096
#define C_DIM 128
#define B_SZ  4

typedef __attribute__((ext_vector_type(8))) short short8;
typedef __attribute__((ext_vector_type(4))) short short4v;
typedef __attribute__((ext_vector_type(4))) float f32x4;

__device__ __forceinline__ short f2bf(float f) {
    union { float fv; unsigned u; } v; v.fv = f;
    unsigned r = v.u + 0x7fff + ((v.u >> 16) & 1);
    return (short)(r >> 16);
}

__device__ __forceinline__ unsigned pk_bf16(float a, float b) {
    union { __hip_bfloat162 h2; unsigned u; } c;
    c.h2 = __float22bfloat162_rn(make_float2(a, b));
    return c.u;
}

__device__ __forceinline__ short8 load_f32x8_bf16(const float* p) {
    const float4* q = (const float4*)p;
    float4 a = q[0], b = q[1];
    short8 r;
    r[0] = f2bf(a.x); r[1] = f2bf(a.y); r[2] = f2bf(a.z); r[3] = f2bf(a.w);
    r[4] = f2bf(b.x); r[5] = f2bf(b.y); r[6] = f2bf(b.z); r[7] = f2bf(b.w);
    return r;
}

// 16B-per-lane async global->LDS DMA (wave-uniform LDS base + lane*16).
__device__ __forceinline__ void async_cp16(const short* g, short* l) {
    __builtin_amdgcn_global_load_lds(
        (const __attribute__((address_space(1))) unsigned int*)g,
        (__attribute__((address_space(3))) unsigned int*)l, 16, 0, 0);
}

// ---------------------------------------------------------------------------
// Kernel 1: QKV projection. R28: FUSED 3-MAT single pass over x.
// Previously 3x128 blocks re-read x per matrix (24 MB HBM). Now 256 blocks
// x 256 thr; each block owns 2 row-tiles, loads its x fragments ONCE, then
// loops m=0..2: stage W_m into LDS -> compute -> store. Per-wave math and
// all three store paths (Q linear, Kf kv-permuted per 16x16 tile: chunk i32
// = contiguous 8 KB at Kf + i32*4096; Vf fragment-ordered) are verbatim
// from R22-R27's verified kernel. Wave (rh = w>>1, nh = w&1) = row-tile x
// nt-half.
// ---------------------------------------------------------------------------
__global__ __launch_bounds__(256) void qkv_proj(
    const float* __restrict__ x, const float* __restrict__ Wq,
    const float* __restrict__ Wk, const float* __restrict__ Wv,
    short* __restrict__ Q, short* __restrict__ Kf, short* __restrict__ Vf)
{
    __shared__ short8 Wl[2048];

    const int tid  = threadIdx.x;
    const int lane = tid & 63;
    const int ln15 = lane & 15;
    const int quad = lane >> 4;
    const int w    = tid >> 6;              // 0..3
    const int rh   = w >> 1;                // row-tile select
    const int nh   = w & 1;                 // nt half select
    const int rt   = blockIdx.x * 2 + rh;   // 0..511
    const int m0   = rt * 32;

    // x fragments for this wave's 32 rows -- loaded ONCE for all 3 mats
    short8 afr[2][4];
#pragma unroll
    for (int ms = 0; ms < 2; ++ms) {
        const float* xrow = x + (size_t)(m0 + ms * 16 + ln15) * C_DIM + quad * 8;
#pragma unroll
        for (int ks = 0; ks < 4; ++ks)
            afr[ms][ks] = load_f32x8_bf16(xrow + ks * 32);
    }

    const int b  = m0 >> 12;
    const int tl = m0 & 4095;

    for (int m = 0; m < 3; ++m) {
        const float* W = (m == 0) ? Wq : (m == 1) ? Wk : Wv;
        __syncthreads();   // Wl free (previous mat's reads done)
#pragma unroll
        for (int it = 0; it < 8; ++it) {
            int i = tid + it * 256;
            int n = i >> 4, kc = i & 15;
            short8 v = load_f32x8_bf16(W + n * C_DIM + kc * 8);
            Wl[((n >> 4) * 4 + (kc >> 2)) * 64 + (kc & 3) * 16 + (n & 15)] = v;
        }
        __syncthreads();   // Wl staged

        const float scale = (m == 0) ? (0.08838834764831845f * 1.4426950408889634f)
                                     : 1.0f;

#pragma unroll
        for (int ntl = 0; ntl < 4; ++ntl) {
            const int nt = nh * 4 + ntl;
            f32x4 acc0 = {0.f, 0.f, 0.f, 0.f};
            f32x4 acc1 = {0.f, 0.f, 0.f, 0.f};
#pragma unroll
            for (int ks = 0; ks < 4; ++ks) {
                short8 bfr = Wl[(nt * 4 + ks) * 64 + lane];
                if (m == 2) {
                    acc0 = __builtin_amdgcn_mfma_f32_16x16x32_bf16(afr[0][ks], bfr, acc0, 0, 0, 0);
                    acc1 = __builtin_amdgcn_mfma_f32_16x16x32_bf16(afr[1][ks], bfr, acc1, 0, 0, 0);
                } else {
                    acc0 = __builtin_amdgcn_mfma_f32_16x16x32_bf16(bfr, afr[0][ks], acc0, 0, 0, 0);
                    acc1 = __builtin_amdgcn_mfma_f32_16x16x32_bf16(bfr, afr[1][ks], acc1, 0, 0, 0);
                }
            }
            if (m == 0) {
                short4v s0, s1;
#pragma unroll
                for (int r = 0; r < 4; ++r) { s0[r] = f2bf(acc0[r] * scale); s1[r] = f2bf(acc1[r] * scale); }
                *(short4v*)&Q[(size_t)(m0 + ln15) * C_DIM + nt * 16 + quad * 4]      = s0;
                *(short4v*)&Q[(size_t)(m0 + 16 + ln15) * C_DIM + nt * 16 + quad * 4] = s1;
            } else if (m == 1) {
                short4v s0, s1;
#pragma unroll
                for (int r = 0; r < 4; ++r) { s0[r] = f2bf(acc0[r]); s1[r] = f2bf(acc1[r]); }
                const int ks     = nt >> 1;
                const int quad_k = (nt & 1) * 2 + (quad >> 1);
                const int j0     = (quad & 1) * 4;
                // ms = 0
                {
                    const int A0 = (tl >> 4) & 3;                 // in {0,2}
                    const int rd = tl >> 6;
                    const int kt = (A0 >> 1) * 2 + ((ln15 >> 2) & 1);
                    const int ar = (((A0 & 1) << 1) | ((ln15 >> 3) & 1)) * 4 + (ln15 & 3);
                    size_t a = ((size_t)b << 19) + (size_t)rd * 8192
                             + (kt * 4 + ks) * 512 + quad_k * 128 + ar * 8 + j0;
                    *(short4v*)&Kf[a] = s0;
                }
                // ms = 1 (t-base = tl + 16)
                {
                    const int A1 = ((tl >> 4) + 1) & 3;           // in {1,3}
                    const int rd = (tl + 16) >> 6;
                    const int kt = (A1 >> 1) * 2 + ((ln15 >> 2) & 1);
                    const int ar = (((A1 & 1) << 1) | ((ln15 >> 3) & 1)) * 4 + (ln15 & 3);
                    size_t a = ((size_t)b << 19) + (size_t)rd * 8192
                             + (kt * 4 + ks) * 512 + quad_k * 128 + ar * 8 + j0;
                    *(short4v*)&Kf[a] = s1;
                }
            } else {
                const int kvc = tl >> 5;
                short4v s0, s1;
#pragma unroll
                for (int r = 0; r < 4; ++r) { s0[r] = f2bf(acc0[r]); s1[r] = f2bf(acc1[r]); }
                short* vbase = Vf + (((size_t)(b * 128 + kvc) * 8 + nt) << 9);
                *(short4v*)&vbase[((quad >> 1) * 16 + ln15) * 8 + (quad & 1) * 4]       = s0;
                *(short4v*)&vbase[(((quad >> 1) + 2) * 16 + ln15) * 8 + (quad & 1) * 4] = s1;
            }
        }
    }
}

// ---------------------------------------------------------------------------
// Kernel 2: causal flash attention. R28 = R25 VERBATIM (session best,
// 108.05 us): fused chunk-pair, 8 waves / 512 thr, complementary-pair
// balance, counted-vmcnt TOP barrier, alias-free 4-array double-buffer,
// partial O/l to part/lpart. R27's fold-in combine reverted: its
// __threadfence lowered to per-block L2 writebacks (FETCH 10->29 MB) and
// the added tail spilled acc (VGPR 104->56) -> 310 us. Separate combine
// kernel restored.
// ---------------------------------------------------------------------------

#define QK8(KARR, SA, SB)                                                    \
    _Pragma("unroll")                                                        \
    for (int ks = 0; ks < 4; ++ks) {                                         \
      SA = __builtin_amdgcn_mfma_f32_16x16x32_bf16(KARR[ks],   qf[ks], SA, 0,0,0); \
      SB = __builtin_amdgcn_mfma_f32_16x16x32_bf16(KARR[4+ks], qf[ks], SB, 0,0,0); \
    }

#define SM8(SA, SB, PA)                                                      \
    {                                                                        \
      float p0 = __builtin_amdgcn_exp2f(SA[0] - 16.f);                       \
      float p1 = __builtin_amdgcn_exp2f(SA[1] - 16.f);                       \
      float p2 = __builtin_amdgcn_exp2f(SA[2] - 16.f);                       \
      float p3 = __builtin_amdgcn_exp2f(SA[3] - 16.f);                       \
      float p4 = __builtin_amdgcn_exp2f(SB[0] - 16.f);                       \
      float p5 = __builtin_amdgcn_exp2f(SB[1] - 16.f);                       \
      float p6 = __builtin_amdgcn_exp2f(SB[2] - 16.f);                       \
      float p7 = __builtin_amdgcn_exp2f(SB[3] - 16.f);                       \
      l_i += ((p0 + p1) + (p2 + p3)) + ((p4 + p5) + (p6 + p7));              \
      PA.u[0] = pk_bf16(p0, p1); PA.u[1] = pk_bf16(p2, p3);                  \
      PA.u[2] = pk_bf16(p4, p5); PA.u[3] = pk_bf16(p6, p7);                  \
    }

#define MASK8(SA, SB, CC)                                                    \
    if (32 * (CC) + 31 > Rw) {                                               \
      const int qcol = Rw + ln15;                                            \
      const int kb   = 32 * (CC) + quad * 8;                                 \
      _Pragma("unroll")                                                      \
      for (int rr = 0; rr < 4; ++rr) {                                       \
        if (kb + rr > qcol)     SA[rr] = -INFINITY;                          \
        if (kb + 4 + rr > qcol) SB[rr] = -INFINITY;                          \
      }                                                                      \
    }

#define PV8(VB_, OFF, PA)                                                    \
    _Pragma("unroll")                                                        \
    for (int dt = 0; dt < 8; ++dt) {                                         \
      short8 vfr = *(const short8*)&(VB_)[(OFF) + dt * 512 + lane * 8];      \
      acc[dt] = __builtin_amdgcn_mfma_f32_16x16x32_bf16(PA.s8, vfr,          \
                                                        acc[dt], 0, 0, 0);   \
    }

// Fused: both chunks of the round active. Chunk0 is never diagonal here.
#define CHUNK2(KB_, VB_, T0)                                                 \
  {                                                                          \
    const int cc1 = qq + 4 * (T0) + 4;                                       \
    short8 kfr0[8];                                                          \
    _Pragma("unroll")                                                        \
    for (int j = 0; j < 8; ++j)                                              \
      kfr0[j] = *(const short8*)&(KB_)[j * 512 + lane * 8];                  \
    __builtin_amdgcn_s_setprio(1);                                           \
    f32x4 Sa0 = {0.f,0.f,0.f,0.f}, Sb0 = {0.f,0.f,0.f,0.f};                  \
    QK8(kfr0, Sa0, Sb0)                                                      \
    short8 kfr1[8];                                                          \
    _Pragma("unroll")                                                        \
    for (int j = 0; j < 8; ++j)                                              \
      kfr1[j] = *(const short8*)&(KB_)[4096 + j * 512 + lane * 8];           \
    f32x4 Sa1 = {0.f,0.f,0.f,0.f}, Sb1 = {0.f,0.f,0.f,0.f};                  \
    QK8(kfr1, Sa1, Sb1)                                                      \
    union { unsigned u[4]; short8 s8; } pa0, pa1;                            \
    SM8(Sa0, Sb0, pa0)                                                       \
    PV8(VB_, 0, pa0)                                                         \
    MASK8(Sa1, Sb1, cc1)                                                     \
    SM8(Sa1, Sb1, pa1)                                                       \
    PV8(VB_, 4096, pa1)                                                      \
    __builtin_amdgcn_s_setprio(0);                                           \
  }

// Single: only chunk0 (slot 0) active.
#define CHUNK1(KB_, VB_, T0)                                                 \
  {                                                                          \
    const int cc0 = qq + 4 * (T0);                                           \
    short8 kfr0[8];                                                          \
    _Pragma("unroll")                                                        \
    for (int j = 0; j < 8; ++j)                                              \
      kfr0[j] = *(const short8*)&(KB_)[j * 512 + lane * 8];                  \
    __builtin_amdgcn_s_setprio(1);                                           \
    f32x4 Sa0 = {0.f,0.f,0.f,0.f}, Sb0 = {0.f,0.f,0.f,0.f};                  \
    QK8(kfr0, Sa0, Sb0)                                                      \
    MASK8(Sa0, Sb0, cc0)                                                     \
    union { unsigned u[4]; short8 s8; } pa0;                                 \
    SM8(Sa0, Sb0, pa0)                                                       \
    PV8(VB_, 0, pa0)                                                         \
    __builtin_amdgcn_s_setprio(0);                                           \
  }

#define ROUND(KC, VC, KN, VN, R)                                             \
  {                                                                          \
    /* TOP: stage(R) complete (issued a full round ago) */                   \
    asm volatile("s_waitcnt vmcnt(0)" ::: "memory");                         \
    __builtin_amdgcn_sched_barrier(0);                                       \
    __builtin_amdgcn_s_barrier();                                            \
    __builtin_amdgcn_sched_barrier(0);                                       \
    /* stage round R+1 (chunks 2R+2, 2R+3) into KN/VN; wave roles:          \
       w0,1->K slot0 | w2,3->K slot1 | w4,5->V slot0 | w6,7->V slot1 */      \
    {                                                                        \
      const int slot = (w >> 1) & 1;                                         \
      const int tS   = 2 * (R) + 2 + slot;                                   \
      if (tS <= gg) {                                                        \
        const int hw = w & 1;                                                \
        const short* src = ((w < 4) ? Kb : Vb)                               \
                         + (size_t)(qq + 4 * tS) * 4096 + hw * 2048;         \
        short* dst = ((w < 4) ? (KN) : (VN)) + slot * 4096 + hw * 2048;      \
        _Pragma("unroll")                                                    \
        for (int i = 0; i < 4; ++i)                                          \
          async_cp16(src + i * 512 + lane * 8, dst + i * 512);               \
      }                                                                      \
    }                                                                        \
    const int t0 = 2 * (R);                                                  \
    const bool a1 = (t0 + 1 <= gg) && (32 * (qq + 4 * t0 + 4) <= Rw + 15);   \
    const bool a0 = (t0 <= gg) && (32 * (qq + 4 * t0) <= Rw + 15);           \
    if (a1)      CHUNK2(KC, VC, t0)                                          \
    else if (a0) CHUNK1(KC, VC, t0)                                          \
  }

__global__ __launch_bounds__(512, 2) void flash_attn(
    const short* __restrict__ Q, const short* __restrict__ Kf,
    const short* __restrict__ Vf, float* __restrict__ part,
    float* __restrict__ lpart)
{
    __shared__ short Kld0[8192];   // 16 KB: 2 kv-chunks (slots), tile-permuted
    __shared__ short Kld1[8192];   // distinct objects: alias-free dbuf
    __shared__ short Vld0[8192];
    __shared__ short Vld1[8192];

    const int tid  = threadIdx.x;
    const int w    = tid >> 6;            // 0..7 = q-tile owner + stage role
    const int lane = tid & 63;
    const int ln15 = lane & 15;
    const int quad = lane >> 4;
    const int bid  = blockIdx.x;

    // complementary-pair balance: bid and bid+256 share a CU; give them
    // gg = 31-x and x so per-CU round-sum is constant.
    const int u     = bid & 255;
    const int ph    = bid >> 8;           // 0: gg descending; 1: ascending
    const int xg    = u >> 3;             // 0..31
    const int gg    = ph ? xg : (31 - xg);
    const int combo = (ph << 3) | (u & 7);  // 0..15, all (b,qq) per gg
    const int b     = combo >> 2;         // batch
    const int qq    = combo & 3;          // kv chunk parity quarter

    const int Rw   = 128 * gg + 16 * w;   // this wave's 16-row base (in-batch)
    const int nrounds = (gg >> 1) + 1;    // chunks t=0..gg, 2 per round

    const short* Qb = Q  + ((size_t)b << 19);
    const short* Kb = Kf + ((size_t)b << 19);
    const short* Vb = Vf + ((size_t)b << 19);

    // Q B-frags for this wave's 16 q-rows
    short8 qf[4];
    {
        const short* qrow = Qb + (size_t)(Rw + ln15) * C_DIM + quad * 8;
#pragma unroll
        for (int ks = 0; ks < 4; ++ks)
            qf[ks] = *(const short8*)(qrow + ks * 32);
    }

    f32x4 acc[8];
#pragma unroll
    for (int dt = 0; dt < 8; ++dt)
        acc[dt] = (f32x4){0.f, 0.f, 0.f, 0.f};
    float l_i = 0.f;

    // prologue: stage round 0 (chunks t=0 slot0, t=1 slot1) into buf0
    {
        const int slot = (w >> 1) & 1;
        const int tS   = slot;
        if (tS <= gg) {
            const int hw = w & 1;
            const short* src = ((w < 4) ? Kb : Vb)
                             + (size_t)(qq + 4 * tS) * 4096 + hw * 2048;
            short* dst = ((w < 4) ? Kld0 : Vld0) + slot * 4096 + hw * 2048;
#pragma unroll
            for (int i = 0; i < 4; ++i)
                async_cp16(src + i * 512 + lane * 8, dst + i * 512);
        }
    }

    int r = 0;
    while (true) {
        ROUND(Kld0, Vld0, Kld1, Vld1, r);
        if (++r >= nrounds) break;
        ROUND(Kld1, Vld1, Kld0, Vld0, r);
        if (++r >= nrounds) break;
    }

    // ---- epilogue: quad-sum l in-register, store partial O + l ----
    l_i += __shfl_xor(l_i, 16);
    l_i += __shfl_xor(l_i, 32);           // all lanes: full l for q-row ln15

    float* pp = part + (((size_t)(qq * 4 + b)) * 4096 + Rw) * 128;
#pragma unroll
    for (int dt = 0; dt < 8; ++dt)
#pragma unroll
        for (int rr = 0; rr < 4; ++rr)
            pp[(quad * 4 + rr) * 128 + dt * 16 + ln15] = acc[dt][rr];
    if (quad == 0)
        lpart[(size_t)(qq * 4 + b) * 4096 + Rw + ln15] = l_i;
}

// ---------------------------------------------------------------------------
// Kernel 3: combine the 4 kv-quarters: out = (Sum_q P_q) / (Sum_q l_q).
// part[quarter*4+b][row][col] is row-major -> fully coalesced f32x4 reads.
// ---------------------------------------------------------------------------
__global__ __launch_bounds__(256) void combine(
    const float* __restrict__ part, const float* __restrict__ lpart,
    float* __restrict__ out)
{
    const int tid = threadIdx.x;
    const int bid = blockIdx.x;

#pragma unroll
    for (int i = 0; i < 8; ++i) {
        int f4  = bid * 2048 + i * 256 + tid;   // [0, 524288)
        int c4  = f4 & 31;
        int row = f4 >> 5;                      // b*4096 + trow
        int b   = row >> 12;
        int trow = row & 4095;

        float4 p = make_float4(0.f, 0.f, 0.f, 0.f);
        float  l = 0.f;
#pragma unroll
        for (int q = 0; q < 4; ++q) {
            size_t base = (((size_t)(q * 4 + b)) * 4096 + trow) * 128 + c4 * 4;
            float4 pq = *(const float4*)&part[base];
            p.x += pq.x; p.y += pq.y; p.z += pq.z; p.w += pq.w;
            l += lpart[(size_t)(q * 4 + b) * 4096 + trow];
        }
        float li = 1.0f / l;
        float4 v;
        v.x = p.x * li; v.y = p.y * li; v.z = p.z * li; v.w = p.w * li;
        ((float4*)out)[f4] = v;
    }
}

extern "C" void kernel_launch(void* const* d_in, const int* in_sizes, int n_in,
                              void* d_out, int out_size, void* d_ws, size_t ws_size,
                              hipStream_t stream) {
    const float* x  = (const float*)d_in[0];
    const float* Wq = (const float*)d_in[1];
    const float* Wk = (const float*)d_in[2];
    const float* Wv = (const float*)d_in[3];
    float* out = (float*)d_out;

    const size_t elems = (size_t)B_SZ * T_SEQ * C_DIM;   // 2,097,152
    short* Q  = (short*)d_ws;
    short* Kf = Q  + elems;
    short* Vf = Kf + elems;
    float* part  = (float*)(Vf + elems);                 // 16 planes x 2 MB
    float* lpart = part + (size_t)16 * 4096 * 128;

    // 256 blocks: fused 3-mat QKV, x read once
    hipLaunchKernelGGL(qkv_proj, dim3(256), dim3(256), 0, stream,
                       x, Wq, Wk, Wv, Q, Kf, Vf);
    // 512 blocks, complementary-pair balanced: bid & bid+256 share a CU
    hipLaunchKernelGGL(flash_attn, dim3(512), dim3(512), 0, stream,
                       Q, Kf, Vf, part, lpart);
    hipLaunchKernelGGL(combine, dim3(256), dim3(256), 0, stream,
                       part, lpart, out);
}

// Round 16
// 107.910 us; speedup vs baseline: 3.2882x; 1.0272x over previous
//
#include <hip/hip_runtime.h>
#include <hip/hip_bf16.h>
#include <math.h>

#define T_SEQ 4096
#define C_DIM 128
#define B_SZ  4

typedef __attribute__((ext_vector_type(8))) short short8;
typedef __attribute__((ext_vector_type(4))) short short4v;
typedef __attribute__((ext_vector_type(4))) float f32x4;

__device__ __forceinline__ short f2bf(float f) {
    union { float fv; unsigned u; } v; v.fv = f;
    unsigned r = v.u + 0x7fff + ((v.u >> 16) & 1);
    return (short)(r >> 16);
}

__device__ __forceinline__ unsigned pk_bf16(float a, float b) {
    union { __hip_bfloat162 h2; unsigned u; } c;
    c.h2 = __float22bfloat162_rn(make_float2(a, b));
    return c.u;
}

__device__ __forceinline__ short8 load_f32x8_bf16(const float* p) {
    const float4* q = (const float4*)p;
    float4 a = q[0], b = q[1];
    short8 r;
    r[0] = f2bf(a.x); r[1] = f2bf(a.y); r[2] = f2bf(a.z); r[3] = f2bf(a.w);
    r[4] = f2bf(b.x); r[5] = f2bf(b.y); r[6] = f2bf(b.z); r[7] = f2bf(b.w);
    return r;
}

// 16B-per-lane async global->LDS DMA (wave-uniform LDS base + lane*16).
__device__ __forceinline__ void async_cp16(const short* g, short* l) {
    __builtin_amdgcn_global_load_lds(
        (const __attribute__((address_space(1))) unsigned int*)g,
        (__attribute__((address_space(3))) unsigned int*)l, 16, 0, 0);
}

// ---------------------------------------------------------------------------
// Kernel 1: QKV projection (R23-R25 proven version, 384 blocks). Kf stored
// KV-PERMUTED per 16x16 tile: kv-chunk i32 (32 kv rows) = contiguous 8 KB
// at Kf + i32*4096 shorts (Vf likewise) so flash's swapped QK^T output is
// directly PV's A-fragment. R29: R28's 3-mat fusion reverted (it serialized
// W stagings at 1 block/CU; x was L3-resident so the saved re-read was
// nearly free anyway).
// ---------------------------------------------------------------------------
__global__ __launch_bounds__(256) void qkv_proj(
    const float* __restrict__ x, const float* __restrict__ Wq,
    const float* __restrict__ Wk, const float* __restrict__ Wv,
    short* __restrict__ Q, short* __restrict__ Kf, short* __restrict__ Vf)
{
    __shared__ short8 Wl[2048];

    const int tid  = threadIdx.x;
    const int lane = tid & 63;
    const int ln15 = lane & 15;
    const int quad = lane >> 4;
    const int mat  = blockIdx.x >> 7;                       // 0..2
    const int rt   = (blockIdx.x & 127) * 4 + (tid >> 6);   // 0..511
    const int m0   = rt * 32;

    const float* W = (mat == 0) ? Wq : (mat == 1) ? Wk : Wv;

#pragma unroll
    for (int it = 0; it < 8; ++it) {
        int i = tid + it * 256;
        int n = i >> 4, kc = i & 15;
        short8 v = load_f32x8_bf16(W + n * C_DIM + kc * 8);
        Wl[((n >> 4) * 4 + (kc >> 2)) * 64 + (kc & 3) * 16 + (n & 15)] = v;
    }

    short8 afr[2][4];
#pragma unroll
    for (int ms = 0; ms < 2; ++ms) {
        const float* xrow = x + (size_t)(m0 + ms * 16 + ln15) * C_DIM + quad * 8;
#pragma unroll
        for (int ks = 0; ks < 4; ++ks)
            afr[ms][ks] = load_f32x8_bf16(xrow + ks * 32);
    }

    __syncthreads();

    const float scale = (mat == 0) ? (0.08838834764831845f * 1.4426950408889634f)
                                   : 1.0f;
    const int b  = m0 >> 12;
    const int tl = m0 & 4095;

#pragma unroll
    for (int nt = 0; nt < 8; ++nt) {
        f32x4 acc0 = {0.f, 0.f, 0.f, 0.f};
        f32x4 acc1 = {0.f, 0.f, 0.f, 0.f};
#pragma unroll
        for (int ks = 0; ks < 4; ++ks) {
            short8 bfr = Wl[(nt * 4 + ks) * 64 + lane];
            if (mat == 2) {
                acc0 = __builtin_amdgcn_mfma_f32_16x16x32_bf16(afr[0][ks], bfr, acc0, 0, 0, 0);
                acc1 = __builtin_amdgcn_mfma_f32_16x16x32_bf16(afr[1][ks], bfr, acc1, 0, 0, 0);
            } else {
                acc0 = __builtin_amdgcn_mfma_f32_16x16x32_bf16(bfr, afr[0][ks], acc0, 0, 0, 0);
                acc1 = __builtin_amdgcn_mfma_f32_16x16x32_bf16(bfr, afr[1][ks], acc1, 0, 0, 0);
            }
        }
        if (mat == 0) {
            short4v s0, s1;
#pragma unroll
            for (int r = 0; r < 4; ++r) { s0[r] = f2bf(acc0[r] * scale); s1[r] = f2bf(acc1[r] * scale); }
            *(short4v*)&Q[(size_t)(m0 + ln15) * C_DIM + nt * 16 + quad * 4]      = s0;
            *(short4v*)&Q[(size_t)(m0 + 16 + ln15) * C_DIM + nt * 16 + quad * 4] = s1;
        } else if (mat == 1) {
            short4v s0, s1;
#pragma unroll
            for (int r = 0; r < 4; ++r) { s0[r] = f2bf(acc0[r]); s1[r] = f2bf(acc1[r]); }
            const int ks     = nt >> 1;
            const int quad_k = (nt & 1) * 2 + (quad >> 1);
            const int j0     = (quad & 1) * 4;
            // ms = 0
            {
                const int A0 = (tl >> 4) & 3;                 // in {0,2}
                const int rd = tl >> 6;
                const int kt = (A0 >> 1) * 2 + ((ln15 >> 2) & 1);
                const int ar = (((A0 & 1) << 1) | ((ln15 >> 3) & 1)) * 4 + (ln15 & 3);
                size_t a = ((size_t)b << 19) + (size_t)rd * 8192
                         + (kt * 4 + ks) * 512 + quad_k * 128 + ar * 8 + j0;
                *(short4v*)&Kf[a] = s0;
            }
            // ms = 1 (t-base = tl + 16)
            {
                const int A1 = ((tl >> 4) + 1) & 3;           // in {1,3}
                const int rd = (tl + 16) >> 6;
                const int kt = (A1 >> 1) * 2 + ((ln15 >> 2) & 1);
                const int ar = (((A1 & 1) << 1) | ((ln15 >> 3) & 1)) * 4 + (ln15 & 3);
                size_t a = ((size_t)b << 19) + (size_t)rd * 8192
                         + (kt * 4 + ks) * 512 + quad_k * 128 + ar * 8 + j0;
                *(short4v*)&Kf[a] = s1;
            }
        } else {
            const int kvc = tl >> 5;
            short4v s0, s1;
#pragma unroll
            for (int r = 0; r < 4; ++r) { s0[r] = f2bf(acc0[r]); s1[r] = f2bf(acc1[r]); }
            short* vbase = Vf + (((size_t)(b * 128 + kvc) * 8 + nt) << 9);
            *(short4v*)&vbase[((quad >> 1) * 16 + ln15) * 8 + (quad & 1) * 4]       = s0;
            *(short4v*)&vbase[(((quad >> 1) + 2) * 16 + ln15) * 8 + (quad & 1) * 4] = s1;
        }
    }
}

// ---------------------------------------------------------------------------
// Kernel 2: causal flash attention. R29 = R25 VERBATIM (session best,
// 108.05 us): fused chunk-pair, 8 waves / 512 thr, complementary-pair
// balance, counted-vmcnt TOP barrier, alias-free 4-array double-buffer,
// partial O/l to part/lpart, separate combine.
// ---------------------------------------------------------------------------

#define QK8(KARR, SA, SB)                                                    \
    _Pragma("unroll")                                                        \
    for (int ks = 0; ks < 4; ++ks) {                                         \
      SA = __builtin_amdgcn_mfma_f32_16x16x32_bf16(KARR[ks],   qf[ks], SA, 0,0,0); \
      SB = __builtin_amdgcn_mfma_f32_16x16x32_bf16(KARR[4+ks], qf[ks], SB, 0,0,0); \
    }

#define SM8(SA, SB, PA)                                                      \
    {                                                                        \
      float p0 = __builtin_amdgcn_exp2f(SA[0] - 16.f);                       \
      float p1 = __builtin_amdgcn_exp2f(SA[1] - 16.f);                       \
      float p2 = __builtin_amdgcn_exp2f(SA[2] - 16.f);                       \
      float p3 = __builtin_amdgcn_exp2f(SA[3] - 16.f);                       \
      float p4 = __builtin_amdgcn_exp2f(SB[0] - 16.f);                       \
      float p5 = __builtin_amdgcn_exp2f(SB[1] - 16.f);                       \
      float p6 = __builtin_amdgcn_exp2f(SB[2] - 16.f);                       \
      float p7 = __builtin_amdgcn_exp2f(SB[3] - 16.f);                       \
      l_i += ((p0 + p1) + (p2 + p3)) + ((p4 + p5) + (p6 + p7));              \
      PA.u[0] = pk_bf16(p0, p1); PA.u[1] = pk_bf16(p2, p3);                  \
      PA.u[2] = pk_bf16(p4, p5); PA.u[3] = pk_bf16(p6, p7);                  \
    }

#define MASK8(SA, SB, CC)                                                    \
    if (32 * (CC) + 31 > Rw) {                                               \
      const int qcol = Rw + ln15;                                            \
      const int kb   = 32 * (CC) + quad * 8;                                 \
      _Pragma("unroll")                                                      \
      for (int rr = 0; rr < 4; ++rr) {                                       \
        if (kb + rr > qcol)     SA[rr] = -INFINITY;                          \
        if (kb + 4 + rr > qcol) SB[rr] = -INFINITY;                          \
      }                                                                      \
    }

#define PV8(VB_, OFF, PA)                                                    \
    _Pragma("unroll")                                                        \
    for (int dt = 0; dt < 8; ++dt) {                                         \
      short8 vfr = *(const short8*)&(VB_)[(OFF) + dt * 512 + lane * 8];      \
      acc[dt] = __builtin_amdgcn_mfma_f32_16x16x32_bf16(PA.s8, vfr,          \
                                                        acc[dt], 0, 0, 0);   \
    }

// Fused: both chunks of the round active. Chunk0 is never diagonal here.
#define CHUNK2(KB_, VB_, T0)                                                 \
  {                                                                          \
    const int cc1 = qq + 4 * (T0) + 4;                                       \
    short8 kfr0[8];                                                          \
    _Pragma("unroll")                                                        \
    for (int j = 0; j < 8; ++j)                                              \
      kfr0[j] = *(const short8*)&(KB_)[j * 512 + lane * 8];                  \
    __builtin_amdgcn_s_setprio(1);                                           \
    f32x4 Sa0 = {0.f,0.f,0.f,0.f}, Sb0 = {0.f,0.f,0.f,0.f};                  \
    QK8(kfr0, Sa0, Sb0)                                                      \
    short8 kfr1[8];                                                          \
    _Pragma("unroll")                                                        \
    for (int j = 0; j < 8; ++j)                                              \
      kfr1[j] = *(const short8*)&(KB_)[4096 + j * 512 + lane * 8];           \
    f32x4 Sa1 = {0.f,0.f,0.f,0.f}, Sb1 = {0.f,0.f,0.f,0.f};                  \
    QK8(kfr1, Sa1, Sb1)                                                      \
    union { unsigned u[4]; short8 s8; } pa0, pa1;                            \
    SM8(Sa0, Sb0, pa0)                                                       \
    PV8(VB_, 0, pa0)                                                         \
    MASK8(Sa1, Sb1, cc1)                                                     \
    SM8(Sa1, Sb1, pa1)                                                       \
    PV8(VB_, 4096, pa1)                                                      \
    __builtin_amdgcn_s_setprio(0);                                           \
  }

// Single: only chunk0 (slot 0) active.
#define CHUNK1(KB_, VB_, T0)                                                 \
  {                                                                          \
    const int cc0 = qq + 4 * (T0);                                           \
    short8 kfr0[8];                                                          \
    _Pragma("unroll")                                                        \
    for (int j = 0; j < 8; ++j)                                              \
      kfr0[j] = *(const short8*)&(KB_)[j * 512 + lane * 8];                  \
    __builtin_amdgcn_s_setprio(1);                                           \
    f32x4 Sa0 = {0.f,0.f,0.f,0.f}, Sb0 = {0.f,0.f,0.f,0.f};                  \
    QK8(kfr0, Sa0, Sb0)                                                      \
    MASK8(Sa0, Sb0, cc0)                                                     \
    union { unsigned u[4]; short8 s8; } pa0;                                 \
    SM8(Sa0, Sb0, pa0)                                                       \
    PV8(VB_, 0, pa0)                                                         \
    __builtin_amdgcn_s_setprio(0);                                           \
  }

#define ROUND(KC, VC, KN, VN, R)                                             \
  {                                                                          \
    /* TOP: stage(R) complete (issued a full round ago) */                   \
    asm volatile("s_waitcnt vmcnt(0)" ::: "memory");                         \
    __builtin_amdgcn_sched_barrier(0);                                       \
    __builtin_amdgcn_s_barrier();                                            \
    __builtin_amdgcn_sched_barrier(0);                                       \
    /* stage round R+1 (chunks 2R+2, 2R+3) into KN/VN; wave roles:          \
       w0,1->K slot0 | w2,3->K slot1 | w4,5->V slot0 | w6,7->V slot1 */      \
    {                                                                        \
      const int slot = (w >> 1) & 1;                                         \
      const int tS   = 2 * (R) + 2 + slot;                                   \
      if (tS <= gg) {                                                        \
        const int hw = w & 1;                                                \
        const short* src = ((w < 4) ? Kb : Vb)                               \
                         + (size_t)(qq + 4 * tS) * 4096 + hw * 2048;         \
        short* dst = ((w < 4) ? (KN) : (VN)) + slot * 4096 + hw * 2048;      \
        _Pragma("unroll")                                                    \
        for (int i = 0; i < 4; ++i)                                          \
          async_cp16(src + i * 512 + lane * 8, dst + i * 512);               \
      }                                                                      \
    }                                                                        \
    const int t0 = 2 * (R);                                                  \
    const bool a1 = (t0 + 1 <= gg) && (32 * (qq + 4 * t0 + 4) <= Rw + 15);   \
    const bool a0 = (t0 <= gg) && (32 * (qq + 4 * t0) <= Rw + 15);           \
    if (a1)      CHUNK2(KC, VC, t0)                                          \
    else if (a0) CHUNK1(KC, VC, t0)                                          \
  }

__global__ __launch_bounds__(512, 2) void flash_attn(
    const short* __restrict__ Q, const short* __restrict__ Kf,
    const short* __restrict__ Vf, float* __restrict__ part,
    float* __restrict__ lpart)
{
    __shared__ short Kld0[8192];   // 16 KB: 2 kv-chunks (slots), tile-permuted
    __shared__ short Kld1[8192];   // distinct objects: alias-free dbuf
    __shared__ short Vld0[8192];
    __shared__ short Vld1[8192];

    const int tid  = threadIdx.x;
    const int w    = tid >> 6;            // 0..7 = q-tile owner + stage role
    const int lane = tid & 63;
    const int ln15 = lane & 15;
    const int quad = lane >> 4;
    const int bid  = blockIdx.x;

    // complementary-pair balance: bid and bid+256 share a CU; give them
    // gg = 31-x and x so per-CU round-sum is constant.
    const int u     = bid & 255;
    const int ph    = bid >> 8;           // 0: gg descending; 1: ascending
    const int xg    = u >> 3;             // 0..31
    const int gg    = ph ? xg : (31 - xg);
    const int combo = (ph << 3) | (u & 7);  // 0..15, all (b,qq) per gg
    const int b     = combo >> 2;         // batch
    const int qq    = combo & 3;          // kv chunk parity quarter

    const int Rw   = 128 * gg + 16 * w;   // this wave's 16-row base (in-batch)
    const int nrounds = (gg >> 1) + 1;    // chunks t=0..gg, 2 per round

    const short* Qb = Q  + ((size_t)b << 19);
    const short* Kb = Kf + ((size_t)b << 19);
    const short* Vb = Vf + ((size_t)b << 19);

    // Q B-frags for this wave's 16 q-rows
    short8 qf[4];
    {
        const short* qrow = Qb + (size_t)(Rw + ln15) * C_DIM + quad * 8;
#pragma unroll
        for (int ks = 0; ks < 4; ++ks)
            qf[ks] = *(const short8*)(qrow + ks * 32);
    }

    f32x4 acc[8];
#pragma unroll
    for (int dt = 0; dt < 8; ++dt)
        acc[dt] = (f32x4){0.f, 0.f, 0.f, 0.f};
    float l_i = 0.f;

    // prologue: stage round 0 (chunks t=0 slot0, t=1 slot1) into buf0
    {
        const int slot = (w >> 1) & 1;
        const int tS   = slot;
        if (tS <= gg) {
            const int hw = w & 1;
            const short* src = ((w < 4) ? Kb : Vb)
                             + (size_t)(qq + 4 * tS) * 4096 + hw * 2048;
            short* dst = ((w < 4) ? Kld0 : Vld0) + slot * 4096 + hw * 2048;
#pragma unroll
            for (int i = 0; i < 4; ++i)
                async_cp16(src + i * 512 + lane * 8, dst + i * 512);
        }
    }

    int r = 0;
    while (true) {
        ROUND(Kld0, Vld0, Kld1, Vld1, r);
        if (++r >= nrounds) break;
        ROUND(Kld1, Vld1, Kld0, Vld0, r);
        if (++r >= nrounds) break;
    }

    // ---- epilogue: quad-sum l in-register, store partial O + l ----
    l_i += __shfl_xor(l_i, 16);
    l_i += __shfl_xor(l_i, 32);           // all lanes: full l for q-row ln15

    float* pp = part + (((size_t)(qq * 4 + b)) * 4096 + Rw) * 128;
#pragma unroll
    for (int dt = 0; dt < 8; ++dt)
#pragma unroll
        for (int rr = 0; rr < 4; ++rr)
            pp[(quad * 4 + rr) * 128 + dt * 16 + ln15] = acc[dt][rr];
    if (quad == 0)
        lpart[(size_t)(qq * 4 + b) * 4096 + Rw + ln15] = l_i;
}

// ---------------------------------------------------------------------------
// Kernel 3: combine the 4 kv-quarters: out = (Sum_q P_q) / (Sum_q l_q).
// part[quarter*4+b][row][col] is row-major -> fully coalesced f32x4 reads.
// ---------------------------------------------------------------------------
__global__ __launch_bounds__(256) void combine(
    const float* __restrict__ part, const float* __restrict__ lpart,
    float* __restrict__ out)
{
    const int tid = threadIdx.x;
    const int bid = blockIdx.x;

#pragma unroll
    for (int i = 0; i < 8; ++i) {
        int f4  = bid * 2048 + i * 256 + tid;   // [0, 524288)
        int c4  = f4 & 31;
        int row = f4 >> 5;                      // b*4096 + trow
        int b   = row >> 12;
        int trow = row & 4095;

        float4 p = make_float4(0.f, 0.f, 0.f, 0.f);
        float  l = 0.f;
#pragma unroll
        for (int q = 0; q < 4; ++q) {
            size_t base = (((size_t)(q * 4 + b)) * 4096 + trow) * 128 + c4 * 4;
            float4 pq = *(const float4*)&part[base];
            p.x += pq.x; p.y += pq.y; p.z += pq.z; p.w += pq.w;
            l += lpart[(size_t)(q * 4 + b) * 4096 + trow];
        }
        float li = 1.0f / l;
        float4 v;
        v.x = p.x * li; v.y = p.y * li; v.z = p.z * li; v.w = p.w * li;
        ((float4*)out)[f4] = v;
    }
}

extern "C" void kernel_launch(void* const* d_in, const int* in_sizes, int n_in,
                              void* d_out, int out_size, void* d_ws, size_t ws_size,
                              hipStream_t stream) {
    const float* x  = (const float*)d_in[0];
    const float* Wq = (const float*)d_in[1];
    const float* Wk = (const float*)d_in[2];
    const float* Wv = (const float*)d_in[3];
    float* out = (float*)d_out;

    const size_t elems = (size_t)B_SZ * T_SEQ * C_DIM;   // 2,097,152
    short* Q  = (short*)d_ws;
    short* Kf = Q  + elems;
    short* Vf = Kf + elems;
    float* part  = (float*)(Vf + elems);                 // 16 planes x 2 MB
    float* lpart = part + (size_t)16 * 4096 * 128;

    hipLaunchKernelGGL(qkv_proj, dim3(384), dim3(256), 0, stream,
                       x, Wq, Wk, Wv, Q, Kf, Vf);
    // 512 blocks, complementary-pair balanced: bid & bid+256 share a CU
    hipLaunchKernelGGL(flash_attn, dim3(512), dim3(512), 0, stream,
                       Q, Kf, Vf, part, lpart);
    hipLaunchKernelGGL(combine, dim3(256), dim3(256), 0, stream,
                       part, lpart, out);
}